// Round 10
// baseline (191.278 us; speedup 1.0000x reference)
//
#include <hip/hip_runtime.h>
#include <math.h>

#define B_    4
#define SEQ_  2048
#define S_    128
#define L_    2304          // SEQ + 2*S
#define DIN   512
#define DK    64
#define NEGINF (-1e30f)
#define SCALE 0.125f
#define NCOLS 2176          // start(128) + mid(2048) key columns in D
#define NMID  8192          // B_*SEQ_
#define NEDGE 1024          // B_*2*S_
#define LE    2304          // edge De row length

typedef _Float16 f16;
typedef __attribute__((ext_vector_type(8))) _Float16 half8;
typedef __attribute__((ext_vector_type(4))) float f32x4;

union U4 { uint4 u; f16 h[8]; half8 v; };

// ---------------------------------------------------------------------------
// k_wsplit: pre-split 9 W matrices into fp16 hi/lo (transposed) + cope split.
// grid (8, 10) x 256. mat==9: cope (64x128) -> copesp[p][hi d | lo d].
// ---------------------------------------------------------------------------
__global__ __launch_bounds__(256) void k_wsplit(
    const float* __restrict__ Wq,  const float* __restrict__ Wk,  const float* __restrict__ Wv,
    const float* __restrict__ Wqs, const float* __restrict__ Wks, const float* __restrict__ Wvs,
    const float* __restrict__ Wqe, const float* __restrict__ Wke, const float* __restrict__ Wve,
    const float* __restrict__ cope,
    f16* __restrict__ Wsp, f16* __restrict__ copesp)
{
    __shared__ float xs[64 * 68];
    const int kt  = blockIdx.x;
    const int mat = blockIdx.y;
    const int tid = threadIdx.x;

    if (mat == 9) {
        if (kt != 0) return;
        for (int half = 0; half < 2; ++half) {
            #pragma unroll
            for (int i = 0; i < 4; ++i) {
                int g = tid + 256 * i;          // 64 d x 16 float4
                int d = g >> 4, p4 = g & 15;
                *(float4*)(xs + d * 68 + p4 * 4) =
                    *(const float4*)(cope + (size_t)d * 128 + half * 64 + p4 * 4);
            }
            __syncthreads();
            if (tid < 128) {
                int pp = tid & 63, hf = tid >> 6;   // 2 halves of d
                int d0 = hf * 32;
                for (int j = 0; j < 32; ++j) {
                    float v = xs[(d0 + j) * 68 + pp];
                    f16 hi = (f16)v;
                    copesp[(size_t)(half * 64 + pp) * 128 + d0 + j]      = hi;
                    copesp[(size_t)(half * 64 + pp) * 128 + 64 + d0 + j] = (f16)(v - (float)hi);
                }
            }
            __syncthreads();
        }
        return;
    }

    const float* W;
    switch (mat) {
        case 0: W = Wq;  break; case 1: W = Wk;  break; case 2: W = Wv;  break;
        case 3: W = Wqs; break; case 4: W = Wks; break; case 5: W = Wvs; break;
        case 6: W = Wqe; break; case 7: W = Wke; break; default: W = Wve; break;
    }
    const int k0  = kt * 64;
    #pragma unroll
    for (int i = 0; i < 4; ++i) {
        int g = tid + 256 * i;
        int k = g >> 4, c4 = g & 15;
        *(float4*)(xs + k * 68 + c4 * 4) = ((const float4*)W)[(size_t)(k0 + k) * 16 + c4];
    }
    __syncthreads();
    const int col = tid & 63, hf = tid >> 6;
    const int kk0 = hf * 16;
    U4 hi0, hi1, lo0, lo1;
    #pragma unroll
    for (int j = 0; j < 8; ++j) {
        float v0 = xs[(kk0 + j) * 68 + col];
        float v1 = xs[(kk0 + 8 + j) * 68 + col];
        hi0.h[j] = (f16)v0; lo0.h[j] = (f16)(v0 - (float)hi0.h[j]);
        hi1.h[j] = (f16)v1; lo1.h[j] = (f16)(v1 - (float)hi1.h[j]);
    }
    f16* dst = Wsp + (size_t)mat * 65536 + (size_t)col * 1024 + k0 + kk0;
    *(uint4*)(dst)       = hi0.u;
    *(uint4*)(dst + 8)   = hi1.u;
    *(uint4*)(dst + 512) = lo0.u;
    *(uint4*)(dst + 520) = lo1.u;
}

// ---------------------------------------------------------------------------
// k_proj v4: same cooperative A+B LDS staging as the verified round-2 kernel,
// but 16 rows/block -> grid 576 (2.25 blocks/CU; LDS 56.8KB allows 2/CU) so
// barrier stalls overlap across co-resident blocks. Wave w: 16 rows x 48 cols
// (3 x 16-col tiles; mapping verified correct in round 6).
// ---------------------------------------------------------------------------
__global__ __launch_bounds__(256) void k_proj(
    const float* __restrict__ x, const f16* __restrict__ Wsp,
    const float* __restrict__ g0, const float* __restrict__ b0,
    const float* __restrict__ gs, const float* __restrict__ bs,
    const float* __restrict__ ge, const float* __restrict__ be,
    f16* __restrict__ qsp, f16* __restrict__ ksp, f16* __restrict__ vhT)
{
    __shared__ f16 As[16 * 136];       // [row][hi 0..63 | lo 64..127 | pad]
    __shared__ f16 Bs[3 * 64 * 136];   // per-mat [col][hi|lo|pad]
    __shared__ float mean_s[16], rstd_s[16];
    const int tid  = threadIdx.x;
    const int row0 = blockIdx.x * 16;
    const int rseq = row0 % L_;
    const int seg  = (rseq < S_) ? 0 : (rseq >= L_ - S_) ? 2 : 1;
    const int mat0 = (seg == 0) ? 3 : (seg == 2) ? 6 : 0;
    const float* gg = (seg == 0) ? gs : (seg == 2) ? ge : g0;
    const float* bb = (seg == 0) ? bs : (seg == 2) ? be : b0;

    // row stats: 16 threads per row, 32 elems each
    {
        const int rr = tid >> 4, qq = tid & 15;
        const float4* xr = (const float4*)(x + (size_t)(row0 + rr) * DIN) + qq * 8;
        float s = 0.f, s2 = 0.f;
        #pragma unroll
        for (int i = 0; i < 8; ++i) {
            float4 v = xr[i];
            s  += v.x + v.y + v.z + v.w;
            s2 += v.x * v.x + v.y * v.y + v.z * v.z + v.w * v.w;
        }
        s  += __shfl_xor(s, 1);  s  += __shfl_xor(s, 2);
        s  += __shfl_xor(s, 4);  s  += __shfl_xor(s, 8);
        s2 += __shfl_xor(s2, 1); s2 += __shfl_xor(s2, 2);
        s2 += __shfl_xor(s2, 4); s2 += __shfl_xor(s2, 8);
        if (qq == 0) {
            float mean = s * (1.f / DIN);
            mean_s[rr] = mean;
            rstd_s[rr] = rsqrtf(s2 * (1.f / DIN) - mean * mean + 1e-5f);
        }
    }

    const int w = tid >> 6, lane = tid & 63;
    const int cl = lane & 15, quad = lane >> 4;

    f32x4 acc[3];
    #pragma unroll
    for (int j = 0; j < 3; ++j) acc[j] = 0.f;

    // per-wave column tiles: cb = 48w + 16j, matrix uniform per (w,j)
    int mj[3], mcj[3];
    #pragma unroll
    for (int j = 0; j < 3; ++j) {
        int cb = 48 * w + 16 * j;
        mj[j]  = cb >> 6;
        mcj[j] = cb & 63;
    }

    for (int kc = 0; kc < DIN; kc += 64) {
        __syncthreads();
        // stage A (LN'd x, hi/lo split): 16 rows x 8 col-groups = 128 units
        if (tid < 128) {
            int r = tid >> 3, c8 = tid & 7;
            const float* xp = x + (size_t)(row0 + r) * DIN + kc + c8 * 8;
            float4 a0 = *(const float4*)xp;
            float4 a1 = *(const float4*)(xp + 4);
            float4 gA = *(const float4*)(gg + kc + c8 * 8);
            float4 gB = *(const float4*)(gg + kc + c8 * 8 + 4);
            float4 bA = *(const float4*)(bb + kc + c8 * 8);
            float4 bB = *(const float4*)(bb + kc + c8 * 8 + 4);
            float mean = mean_s[r], rstd = rstd_s[r];
            float n[8];
            n[0] = (a0.x - mean) * rstd * gA.x + bA.x;
            n[1] = (a0.y - mean) * rstd * gA.y + bA.y;
            n[2] = (a0.z - mean) * rstd * gA.z + bA.z;
            n[3] = (a0.w - mean) * rstd * gA.w + bA.w;
            n[4] = (a1.x - mean) * rstd * gB.x + bB.x;
            n[5] = (a1.y - mean) * rstd * gB.y + bB.y;
            n[6] = (a1.z - mean) * rstd * gB.z + bB.z;
            n[7] = (a1.w - mean) * rstd * gB.w + bB.w;
            U4 hi, lo;
            #pragma unroll
            for (int j = 0; j < 8; ++j) {
                hi.h[j] = (f16)n[j];
                lo.h[j] = (f16)(n[j] - (float)hi.h[j]);
            }
            *(uint4*)(As + r * 136 + c8 * 8)      = hi.u;
            *(uint4*)(As + r * 136 + 64 + c8 * 8) = lo.u;
        }
        // stage B for all 3 mats: 3 x 64 cols x 8 groups = 1536 units
        #pragma unroll
        for (int i = 0; i < 6; ++i) {
            int g = tid + 256 * i;
            int mm = g >> 9, rem = g & 511;
            int col = rem >> 3, c8 = rem & 7;
            const f16* src = Wsp + (size_t)(mat0 + mm) * 65536 + (size_t)col * 1024 + kc + c8 * 8;
            f16* dst = Bs + mm * 8704 + col * 136 + c8 * 8;
            *(uint4*)(dst)      = *(const uint4*)(src);
            *(uint4*)(dst + 64) = *(const uint4*)(src + 512);
        }
        __syncthreads();
        #pragma unroll
        for (int h = 0; h < 2; ++h) {
            half8 ah, al;
            {
                const f16* base = As + cl * 136 + h * 32 + quad * 8;
                ah = *(const half8*)(base);
                al = *(const half8*)(base + 64);
            }
            #pragma unroll
            for (int j = 0; j < 3; ++j) {
                const f16* base = Bs + mj[j] * 8704 + (mcj[j] + cl) * 136 + h * 32 + quad * 8;
                half8 bh = *(const half8*)(base);
                half8 bl = *(const half8*)(base + 64);
                acc[j] = __builtin_amdgcn_mfma_f32_16x16x32_f16(ah, bh, acc[j], 0, 0, 0);
                acc[j] = __builtin_amdgcn_mfma_f32_16x16x32_f16(ah, bl, acc[j], 0, 0, 0);
                acc[j] = __builtin_amdgcn_mfma_f32_16x16x32_f16(al, bh, acc[j], 0, 0, 0);
            }
        }
    }

    const int bI = row0 / L_;
    const int rb = row0 - bI * L_;
    #pragma unroll
    for (int j = 0; j < 3; ++j) {
        const int mat  = mj[j];
        const int mcol = mcj[j] + cl;
        #pragma unroll
        for (int r = 0; r < 4; ++r) {
            int lrow = quad * 4 + r;
            float v  = acc[j][r];
            size_t grow = (size_t)(row0 + lrow);
            if (mat < 2) {
                f16* sp = (mat == 0) ? qsp : ksp;
                f16 hv = (f16)v;
                sp[grow * 128 + mcol]      = hv;
                sp[grow * 128 + 64 + mcol] = (f16)(v - (float)hv);
            } else {
                vhT[(size_t)(bI * 64 + mcol) * L_ + rb + lrow] = (f16)v;
            }
        }
    }
}

// ---------------------------------------------------------------------------
// k_dots: mid + edge dots via split-fp16 MFMA (round-2 verified core), PLUS
// li = q.cope folded into the 64 formerly-idle block slots (edge half==0,
// by 1..16). grid (72,18) x 256.
// ---------------------------------------------------------------------------
__global__ __launch_bounds__(256) void k_dots(
    const f16* __restrict__ qsp, const f16* __restrict__ ksp,
    const f16* __restrict__ copesp,
    float* __restrict__ D32, float* __restrict__ G, float* __restrict__ De32,
    float* __restrict__ li32)
{
    const int bx = blockIdx.x, by = blockIdx.y;
    const bool edge = (bx >= 64);
    const int tid = threadIdx.x;
    const int w = tid >> 6, lane = tid & 63;
    const int cl = lane & 15, quad = lane >> 4;

    int b, q0 = 0;
    size_t qrow0;
    if (!edge) {
        if (by >= 17) return;                 // NCOLS = 17 * 128
        b = bx >> 4;
        q0 = (bx * 128) & 2047;
        qrow0 = (size_t)b * L_ + S_ + q0;
    } else {
        int ex = bx - 64;
        b = ex >> 1;
        int half = ex & 1;
        if (half == 0 && by > 0) {
            // ---- li region: 64 blocks (ex in {0,2,4,6}, by 1..16) ----
            if (by > 16) return;
            const int id  = (ex >> 1) * 16 + (by - 1);   // 0..63
            const int gr0 = id * 128;
            const int lb  = gr0 >> 11, lq0 = gr0 & 2047;
            const size_t rowb = (size_t)lb * L_ + S_ + lq0 + 32 * w;

            half8 ah[2][2], al[2][2];
            #pragma unroll
            for (int rs = 0; rs < 2; ++rs)
                #pragma unroll
                for (int h = 0; h < 2; ++h) {
                    const f16* qp = qsp + (rowb + 16 * rs + cl) * 128 + h * 32 + quad * 8;
                    ah[rs][h] = *(const half8*)qp;
                    al[rs][h] = *(const half8*)(qp + 64);
                }
            f32x4 acc[2][8];
            #pragma unroll
            for (int rs = 0; rs < 2; ++rs)
                #pragma unroll
                for (int cf = 0; cf < 8; ++cf) acc[rs][cf] = 0.f;
            #pragma unroll
            for (int h = 0; h < 2; ++h)
                #pragma unroll
                for (int cf = 0; cf < 8; ++cf) {
                    const f16* bbase = copesp + (size_t)(16 * cf + cl) * 128 + h * 32 + quad * 8;
                    half8 bh = *(const half8*)bbase;
                    half8 bl = *(const half8*)(bbase + 64);
                    #pragma unroll
                    for (int rs = 0; rs < 2; ++rs) {
                        acc[rs][cf] = __builtin_amdgcn_mfma_f32_16x16x32_f16(ah[rs][h], bh, acc[rs][cf], 0, 0, 0);
                        acc[rs][cf] = __builtin_amdgcn_mfma_f32_16x16x32_f16(ah[rs][h], bl, acc[rs][cf], 0, 0, 0);
                        acc[rs][cf] = __builtin_amdgcn_mfma_f32_16x16x32_f16(al[rs][h], bh, acc[rs][cf], 0, 0, 0);
                    }
                }
            #pragma unroll
            for (int rs = 0; rs < 2; ++rs)
                #pragma unroll
                for (int cf = 0; cf < 8; ++cf)
                    #pragma unroll
                    for (int r = 0; r < 4; ++r) {
                        int row = gr0 + 32 * w + 16 * rs + quad * 4 + r;
                        li32[(size_t)row * 128 + 16 * cf + cl] = acc[rs][cf][r];
                    }
            return;
        }
        qrow0 = (size_t)b * L_ + (half ? 2176 : 0);
    }
    const int col0 = by * 128;
    const size_t krow0 = (size_t)b * L_ + col0;

    __shared__ f16 Qs[128 * 136];
    __shared__ f16 Ks[128 * 136];

    #pragma unroll
    for (int i = 0; i < 8; ++i) {
        int g = tid + 256 * i;
        int r = g >> 4, c = g & 15;
        *(uint4*)(Qs + r * 136 + c * 8) = *(const uint4*)(qsp + (qrow0 + r) * 128 + c * 8);
        *(uint4*)(Ks + r * 136 + c * 8) = *(const uint4*)(ksp + (krow0 + r) * 128 + c * 8);
    }
    __syncthreads();

    f32x4 acc[2][8];
    #pragma unroll
    for (int i = 0; i < 2; ++i)
        #pragma unroll
        for (int j = 0; j < 8; ++j) acc[i][j] = 0.f;

    #pragma unroll
    for (int h = 0; h < 2; ++h) {
        half8 ah[2], al[2];
        #pragma unroll
        for (int rs = 0; rs < 2; ++rs) {
            const f16* base = Qs + (32 * w + 16 * rs + cl) * 136 + h * 32 + quad * 8;
            ah[rs] = *(const half8*)(base);
            al[rs] = *(const half8*)(base + 64);
        }
        #pragma unroll
        for (int cq = 0; cq < 2; ++cq) {
            half8 bh[4], bl[4];
            #pragma unroll
            for (int cc = 0; cc < 4; ++cc) {
                const f16* base = Ks + (16 * (cq * 4 + cc) + cl) * 136 + h * 32 + quad * 8;
                bh[cc] = *(const half8*)(base);
                bl[cc] = *(const half8*)(base + 64);
            }
            #pragma unroll
            for (int rs = 0; rs < 2; ++rs)
                #pragma unroll
                for (int cc = 0; cc < 4; ++cc) {
                    int c = cq * 4 + cc;
                    acc[rs][c] = __builtin_amdgcn_mfma_f32_16x16x32_f16(ah[rs], bh[cc], acc[rs][c], 0, 0, 0);
                    acc[rs][c] = __builtin_amdgcn_mfma_f32_16x16x32_f16(ah[rs], bl[cc], acc[rs][c], 0, 0, 0);
                    acc[rs][c] = __builtin_amdgcn_mfma_f32_16x16x32_f16(al[rs], bh[cc], acc[rs][c], 0, 0, 0);
                }
        }
    }

    if (!edge) {
        const int gr0 = bx * 128;
        const bool writeD = (by == 0) || ((by - 1) <= (q0 >> 7));
        if (writeD) {
            #pragma unroll
            for (int rs = 0; rs < 2; ++rs)
                #pragma unroll
                for (int c = 0; c < 8; ++c)
                    #pragma unroll
                    for (int r = 0; r < 4; ++r) {
                        int mrow = gr0 + 32 * w + 16 * rs + quad * 4 + r;
                        int n    = col0 + 16 * c + cl;
                        D32[(size_t)mrow * NCOLS + n] = acc[rs][c][r];
                    }
        }
        if (by >= 1) {
            const int chm = 2 * (by - 1);
            #pragma unroll
            for (int rs = 0; rs < 2; ++rs)
                #pragma unroll
                for (int r = 0; r < 4; ++r) {
                    float sA = 0.f, sB = 0.f;
                    #pragma unroll
                    for (int cc = 0; cc < 4; ++cc) {
                        sA += 1.f / (1.f + __expf(-acc[rs][cc][r]));
                        sB += 1.f / (1.f + __expf(-acc[rs][4 + cc][r]));
                    }
                    #pragma unroll
                    for (int off = 1; off < 16; off <<= 1) {
                        sA += __shfl_xor(sA, off);
                        sB += __shfl_xor(sB, off);
                    }
                    if (cl == 0) {
                        int row = gr0 + 32 * w + 16 * rs + quad * 4 + r;
                        G[(size_t)row * 32 + chm]     = sA;
                        G[(size_t)row * 32 + chm + 1] = sB;
                    }
                }
        }
    } else {
        const int er0 = (bx - 64) * 128;
        #pragma unroll
        for (int rs = 0; rs < 2; ++rs)
            #pragma unroll
            for (int c = 0; c < 8; ++c)
                #pragma unroll
                for (int r = 0; r < 4; ++r) {
                    int erow = er0 + 32 * w + 16 * rs + quad * 4 + r;
                    int n    = col0 + 16 * c + cl;
                    De32[(size_t)erow * LE + n] = acc[rs][c][r];
                }
    }
}

// ---------------------------------------------------------------------------
// k_scan: grid 9216 x 256. Reads exact fp32 dots + precomputed li; fp16 P.
// Edge path: loads predicated on causal bound (start rows skip 8/9 groups).
// ---------------------------------------------------------------------------
__global__ __launch_bounds__(256) void k_scan(
    const float* __restrict__ li32, const float* __restrict__ G,
    const float* __restrict__ D32, f16* __restrict__ Dp,
    const float* __restrict__ De32, f16* __restrict__ Dep)
{
    __shared__ float li[128];
    __shared__ float Gs[32];
    __shared__ float Gsf[32];
    __shared__ float wmax[4], wsum[4];
    const int tid = threadIdx.x;
    const int gr  = blockIdx.x;
    const int lane = tid & 63, wid = tid >> 6;

    if (gr < NMID) {
        const int b = gr >> 11;
        const int q = gr & 2047;
        const int qlim = (q & ~63) + 64;

        if (tid < 128) li[tid] = li32[(size_t)gr * 128 + tid];
        if (tid >= 128 && tid < 136)
            ((float4*)Gs)[tid - 128] = ((const float4*)G)[(size_t)gr * 8 + tid - 128];
        __syncthreads();
        if (tid >= 128 && tid < 160) {
            int c = tid - 128;
            float s = 0.f;
            for (int cc = c + 1; cc < 32; ++cc) s += Gs[cc];
            Gsf[c] = s;
        }

        const float* Sr = D32 + (size_t)gr * NCOLS;
        f16* Dr = Dp + (size_t)gr * NCOLS;
        const int j0 = tid * 8;
        const int cg = tid >> 3, sl = tid & 7;
        float dot[8], gte[8];
        float csum = 0.f;
        if (j0 < qlim) {
            float4 t0 = *(const float4*)(Sr + 128 + j0);
            float4 t1 = *(const float4*)(Sr + 128 + j0 + 4);
            dot[0] = t0.x; dot[1] = t0.y; dot[2] = t0.z; dot[3] = t0.w;
            dot[4] = t1.x; dot[5] = t1.y; dot[6] = t1.z; dot[7] = t1.w;
            #pragma unroll
            for (int jj = 0; jj < 8; ++jj) {
                gte[jj] = 1.f / (1.f + __expf(-dot[jj]));
                csum += gte[jj];
            }
        } else {
            #pragma unroll
            for (int jj = 0; jj < 8; ++jj) { dot[jj] = 0.f; gte[jj] = 0.f; }
        }
        float sv = (tid < 128) ? Sr[tid] * SCALE : NEGINF;

        float inc = csum;
        #pragma unroll
        for (int off = 1; off < 8; off <<= 1) {
            float u = __shfl_down(inc, off, 8);
            if (sl + off < 8) inc += u;
        }
        __syncthreads();
        float run = (inc - csum) + Gsf[cg];

        float p8[8];
        #pragma unroll
        for (int jj = 7; jj >= 0; --jj) {
            run += gte[jj];
            float pos = fminf(run, (float)(S_ - 1));
            float pfl = floorf(pos);
            int ic  = (int)ceilf(pos);
            int ifl = (int)pfl;
            float w = pos - pfl;
            float bias = li[ic] * w + li[ifl] * (1.f - w);
            p8[jj] = (j0 + jj <= q) ? dot[jj] * SCALE + bias : NEGINF;
        }

        float mx = sv;
        #pragma unroll
        for (int jj = 0; jj < 8; ++jj) mx = fmaxf(mx, p8[jj]);
        #pragma unroll
        for (int off = 1; off < 64; off <<= 1) mx = fmaxf(mx, __shfl_xor(mx, off));
        if (lane == 0) wmax[wid] = mx;
        __syncthreads();
        mx = fmaxf(fmaxf(wmax[0], wmax[1]), fmaxf(wmax[2], wmax[3]));

        float lsum = 0.f;
        float e8[8];
        #pragma unroll
        for (int jj = 0; jj < 8; ++jj) {
            e8[jj] = __expf(p8[jj] - mx);
            lsum += e8[jj];
        }
        float es = 0.f;
        if (tid < 128) { es = __expf(sv - mx); lsum += es; }
        #pragma unroll
        for (int off = 1; off < 64; off <<= 1) lsum += __shfl_xor(lsum, off);
        if (lane == 0) wsum[wid] = lsum;
        __syncthreads();
        float inv = 1.f / (wsum[0] + wsum[1] + wsum[2] + wsum[3]);

        if (j0 < qlim) {
            U4 o;
            #pragma unroll
            for (int jj = 0; jj < 8; ++jj) o.h[jj] = (f16)(e8[jj] * inv);
            *(uint4*)(Dr + 128 + j0) = o.u;
        }
        if (tid < 128) Dr[tid] = (f16)(es * inv);
    } else {
        const int er = gr - NMID;
        const int r  = er & 255;
        const int Q  = (r < 128) ? r : (2048 + r);
        const float* Er32 = De32 + (size_t)er * LE;
        f16* Er = Dep + (size_t)er * LE;

        float v[9];
        #pragma unroll
        for (int i = 0; i < 9; ++i) {
            int j = tid + 256 * i;
            v[i] = (j <= Q) ? Er32[j] * SCALE : NEGINF;   // predicated load
        }
        float mx = v[0];
        #pragma unroll
        for (int i = 1; i < 9; ++i) mx = fmaxf(mx, v[i]);
        #pragma unroll
        for (int off = 1; off < 64; off <<= 1) mx = fmaxf(mx, __shfl_xor(mx, off));
        if (lane == 0) wmax[wid] = mx;
        __syncthreads();
        mx = fmaxf(fmaxf(wmax[0], wmax[1]), fmaxf(wmax[2], wmax[3]));

        float lsum = 0.f;
        #pragma unroll
        for (int i = 0; i < 9; ++i) {
            v[i] = __expf(v[i] - mx);
            lsum += v[i];
        }
        #pragma unroll
        for (int off = 1; off < 64; off <<= 1) lsum += __shfl_xor(lsum, off);
        if (lane == 0) wsum[wid] = lsum;
        __syncthreads();
        float inv = 1.f / (wsum[0] + wsum[1] + wsum[2] + wsum[3]);

        #pragma unroll
        for (int i = 0; i < 9; ++i)
            Er[tid + 256 * i] = (f16)(v[i] * inv);
    }
}

// ---------------------------------------------------------------------------
// k_pv (round-2 verified): mid + edge PV via fp16 MFMA, 4-way K-split,
// partial stores. grid (144, 4) x 256. bx<128: mid. bx>=128: edge.
// ---------------------------------------------------------------------------
__global__ __launch_bounds__(256) void k_pv(
    const f16* __restrict__ Pmid, const f16* __restrict__ Pedge,
    const f16* __restrict__ vhT,
    float* __restrict__ Opart, float* __restrict__ Oe)
{
    __shared__ f16 Ps[64 * 72];
    __shared__ f16 Vt[64 * 72];
    const int tid = threadIdx.x;
    const int bx  = blockIdx.x;
    const int ks  = blockIdx.y;
    const bool edge = (bx >= 128);

    const f16* Pb;
    size_t pitch;
    int row0, b, cap, cmax;
    float* outp;
    if (!edge) {
        row0 = bx * 64;
        b = row0 >> 11;
        int q0 = row0 & 2047;
        Pb = Pmid; pitch = NCOLS; cap = 34;
        cmax = (191 + q0) >> 6;
        outp = Opart + (size_t)ks * NMID * DK;
    } else {
        row0 = (bx - 128) * 64;
        b = row0 >> 8;
        int r0 = row0 & 255;
        Pb = Pedge; pitch = LE; cap = 36;
        int Qmax = (r0 < 128) ? (r0 + 63) : (2048 + r0 + 63);
        cmax = Qmax >> 6;
        outp = Oe + (size_t)ks * NEDGE * DK;
    }
    const int c_beg = ks * 9;
    int c_end = c_beg + 9;
    if (c_end > cap) c_end = cap;
    if (c_end > cmax + 1) c_end = cmax + 1;

    const int w = tid >> 6, lane = tid & 63;
    const int cl = lane & 15, quad = lane >> 4;
    f32x4 acc[4];
    #pragma unroll
    for (int c = 0; c < 4; ++c) acc[c] = 0.f;

    for (int ch = c_beg; ch < c_end; ++ch) {
        __syncthreads();
        #pragma unroll
        for (int i = 0; i < 2; ++i) {
            int g = tid + 256 * i;
            int r = g >> 3, c = g & 7;
            *(uint4*)(Ps + r * 72 + c * 8) =
                *(const uint4*)(Pb + (size_t)(row0 + r) * pitch + ch * 64 + c * 8);
            *(uint4*)(Vt + r * 72 + c * 8) =
                *(const uint4*)(vhT + (size_t)(b * 64 + r) * L_ + ch * 64 + c * 8);
        }
        __syncthreads();
        #pragma unroll
        for (int h = 0; h < 2; ++h) {
            half8 a = *(const half8*)(Ps + (16 * w + cl) * 72 + h * 32 + quad * 8);
            #pragma unroll
            for (int c = 0; c < 4; ++c) {
                half8 bv = *(const half8*)(Vt + (16 * c + cl) * 72 + h * 32 + quad * 8);
                acc[c] = __builtin_amdgcn_mfma_f32_16x16x32_f16(a, bv, acc[c], 0, 0, 0);
            }
        }
    }
    #pragma unroll
    for (int c = 0; c < 4; ++c)
        #pragma unroll
        for (int r = 0; r < 4; ++r) {
            int mrow = row0 + 16 * w + quad * 4 + r;
            int n    = 16 * c + cl;
            outp[(size_t)mrow * DK + n] = acc[c][r];
        }
}

// ---------------------------------------------------------------------------
// k_merge (round-2 verified): sum 4 partials, mid + edge. grid 2304 x 256.
// ---------------------------------------------------------------------------
__global__ __launch_bounds__(256) void k_merge(
    const float* __restrict__ Opart, const float* __restrict__ Oe,
    float* __restrict__ out)
{
    const int e = blockIdx.x * 256 + threadIdx.x;
    if (e < NMID * DK) {
        const int gr = e >> 6, c = e & 63;
        const int b  = gr >> 11, q = gr & 2047;
        const int NP = NMID * DK;
        float s = Opart[e] + Opart[e + NP] + Opart[e + 2 * NP] + Opart[e + 3 * NP];
        out[((size_t)b * L_ + S_ + q) * DK + c] = s;
    } else {
        const int e2 = e - NMID * DK;
        const int er = e2 >> 6, c = e2 & 63;
        const int b  = er >> 8, r = er & 255;
        const int gQ = (r < 128) ? r : (2048 + r);
        const int NP = NEDGE * DK;
        float s = Oe[e2] + Oe[e2 + NP] + Oe[e2 + 2 * NP] + Oe[e2 + 3 * NP];
        out[((size_t)b * L_ + gQ) * DK + c] = s;
    }
}

// ---------------------------------------------------------------------------
extern "C" void kernel_launch(void* const* d_in, const int* in_sizes, int n_in,
                              void* d_out, int out_size, void* d_ws, size_t ws_size,
                              hipStream_t stream)
{
    const float* x    = (const float*)d_in[0];
    const float* Wq   = (const float*)d_in[1];
    const float* Wk   = (const float*)d_in[2];
    const float* Wv   = (const float*)d_in[3];
    const float* Wqs  = (const float*)d_in[4];
    const float* Wks  = (const float*)d_in[5];
    const float* Wvs  = (const float*)d_in[6];
    const float* Wqe  = (const float*)d_in[7];
    const float* Wke  = (const float*)d_in[8];
    const float* Wve  = (const float*)d_in[9];
    const float* g0   = (const float*)d_in[10];
    const float* b0   = (const float*)d_in[11];
    const float* gs   = (const float*)d_in[12];
    const float* bs   = (const float*)d_in[13];
    const float* ge   = (const float*)d_in[14];
    const float* be   = (const float*)d_in[15];
    const float* cope = (const float*)d_in[16];

    const size_t NR = (size_t)B_ * L_;                 // 9216 rows
    f16*   qsp    = (f16*)d_ws;                        // NR*128 h (hi|lo)
    f16*   ksp    = qsp + NR * 128;                    // NR*128 h
    f16*   vhT    = ksp + NR * 128;                    // NR*64 h
    f16*   Wsp    = vhT + NR * 64;                     // 9*65536 h
    f16*   copesp = Wsp + (size_t)9 * 65536;           // 128*128 h
    float* G      = (float*)(copesp + 16384);          // NMID*32 f32
    float* li32   = G + (size_t)NMID * 32;             // NMID*128 f32
    float* Opart  = li32 + (size_t)NMID * 128;         // 4*NMID*64 f32
    float* Oe     = Opart + (size_t)4 * NMID * DK;     // 4*NEDGE*64 f32
    float* Dm32   = Oe + (size_t)4 * NEDGE * DK;       // NMID*NCOLS f32
    float* De32   = Dm32 + (size_t)NMID * NCOLS;       // NEDGE*LE f32
    f16*   Dp     = (f16*)(De32 + (size_t)NEDGE * LE); // NMID*NCOLS h (P)
    f16*   Dep    = Dp + (size_t)NMID * NCOLS;         // NEDGE*LE h (P)
    float* out    = (float*)d_out;

    k_wsplit<<<dim3(8, 10), 256, 0, stream>>>(Wq, Wk, Wv, Wqs, Wks, Wvs,
                                              Wqe, Wke, Wve, cope, Wsp, copesp);
    k_proj<<<576, 256, 0, stream>>>(x, Wsp, g0, b0, gs, bs, ge, be,
                                    qsp, ksp, vhT);
    k_dots<<<dim3(72, 18), 256, 0, stream>>>(qsp, ksp, copesp, Dm32, G, De32, li32);
    k_scan<<<NMID + NEDGE, 256, 0, stream>>>(li32, G, Dm32, Dp, De32, Dep);
    k_pv  <<<dim3(144, 4), 256, 0, stream>>>(Dp, Dep, vhT, Opart, Oe);
    k_merge<<<(NMID + NEDGE) * DK / 256, 256, 0, stream>>>(Opart, Oe, out);
}

// Round 11
// 186.309 us; speedup vs baseline: 1.0267x; 1.0267x over previous
//
#include <hip/hip_runtime.h>
#include <math.h>

#define B_    4
#define SEQ_  2048
#define S_    128
#define L_    2304          // SEQ + 2*S
#define DIN   512
#define DK    64
#define NEGINF (-1e30f)
#define SCALE 0.125f
#define NCOLS 2176          // start(128) + mid(2048) key columns in D
#define NMID  8192          // B_*SEQ_
#define NEDGE 1024          // B_*2*S_
#define LE    2304          // edge De row length

typedef _Float16 f16;
typedef __attribute__((ext_vector_type(8))) _Float16 half8;
typedef __attribute__((ext_vector_type(4))) float f32x4;

union U4 { uint4 u; f16 h[8]; half8 v; };

// ---------------------------------------------------------------------------
// k_wsplit: pre-split 9 W matrices into fp16 hi/lo (transposed) + cope split.
// grid (8, 10) x 256. mat==9: cope (64x128) -> copesp[p][hi d | lo d].
// ---------------------------------------------------------------------------
__global__ __launch_bounds__(256) void k_wsplit(
    const float* __restrict__ Wq,  const float* __restrict__ Wk,  const float* __restrict__ Wv,
    const float* __restrict__ Wqs, const float* __restrict__ Wks, const float* __restrict__ Wvs,
    const float* __restrict__ Wqe, const float* __restrict__ Wke, const float* __restrict__ Wve,
    const float* __restrict__ cope,
    f16* __restrict__ Wsp, f16* __restrict__ copesp)
{
    __shared__ float xs[64 * 68];
    const int kt  = blockIdx.x;
    const int mat = blockIdx.y;
    const int tid = threadIdx.x;

    if (mat == 9) {
        if (kt != 0) return;
        for (int half = 0; half < 2; ++half) {
            #pragma unroll
            for (int i = 0; i < 4; ++i) {
                int g = tid + 256 * i;          // 64 d x 16 float4
                int d = g >> 4, p4 = g & 15;
                *(float4*)(xs + d * 68 + p4 * 4) =
                    *(const float4*)(cope + (size_t)d * 128 + half * 64 + p4 * 4);
            }
            __syncthreads();
            if (tid < 128) {
                int pp = tid & 63, hf = tid >> 6;   // 2 halves of d
                int d0 = hf * 32;
                for (int j = 0; j < 32; ++j) {
                    float v = xs[(d0 + j) * 68 + pp];
                    f16 hi = (f16)v;
                    copesp[(size_t)(half * 64 + pp) * 128 + d0 + j]      = hi;
                    copesp[(size_t)(half * 64 + pp) * 128 + 64 + d0 + j] = (f16)(v - (float)hi);
                }
            }
            __syncthreads();
        }
        return;
    }

    const float* W;
    switch (mat) {
        case 0: W = Wq;  break; case 1: W = Wk;  break; case 2: W = Wv;  break;
        case 3: W = Wqs; break; case 4: W = Wks; break; case 5: W = Wvs; break;
        case 6: W = Wqe; break; case 7: W = Wke; break; default: W = Wve; break;
    }
    const int k0  = kt * 64;
    #pragma unroll
    for (int i = 0; i < 4; ++i) {
        int g = tid + 256 * i;
        int k = g >> 4, c4 = g & 15;
        *(float4*)(xs + k * 68 + c4 * 4) = ((const float4*)W)[(size_t)(k0 + k) * 16 + c4];
    }
    __syncthreads();
    const int col = tid & 63, hf = tid >> 6;
    const int kk0 = hf * 16;
    U4 hi0, hi1, lo0, lo1;
    #pragma unroll
    for (int j = 0; j < 8; ++j) {
        float v0 = xs[(kk0 + j) * 68 + col];
        float v1 = xs[(kk0 + 8 + j) * 68 + col];
        hi0.h[j] = (f16)v0; lo0.h[j] = (f16)(v0 - (float)hi0.h[j]);
        hi1.h[j] = (f16)v1; lo1.h[j] = (f16)(v1 - (float)hi1.h[j]);
    }
    f16* dst = Wsp + (size_t)mat * 65536 + (size_t)col * 1024 + k0 + kk0;
    *(uint4*)(dst)       = hi0.u;
    *(uint4*)(dst + 8)   = hi1.u;
    *(uint4*)(dst + 512) = lo0.u;
    *(uint4*)(dst + 520) = lo1.u;
}

// ---------------------------------------------------------------------------
// k_proj (round-2 verified): fused LayerNorm + all three projections,
// cooperative LDS staging of A and B per k-step. grid 288 x 256.
// ---------------------------------------------------------------------------
__global__ __launch_bounds__(256) void k_proj(
    const float* __restrict__ x, const f16* __restrict__ Wsp,
    const float* __restrict__ g0, const float* __restrict__ b0,
    const float* __restrict__ gs, const float* __restrict__ bs,
    const float* __restrict__ ge, const float* __restrict__ be,
    f16* __restrict__ qsp, f16* __restrict__ ksp, f16* __restrict__ vhT)
{
    __shared__ f16 As[32 * 136];       // [row][hi 0..63 | lo 64..127 | pad]
    __shared__ f16 Bs[3 * 64 * 136];   // per-mat [col][hi|lo|pad]
    __shared__ float mean_s[32], rstd_s[32];
    const int tid  = threadIdx.x;
    const int row0 = blockIdx.x * 32;
    const int rseq = row0 % L_;
    const int seg  = (rseq < S_) ? 0 : (rseq >= L_ - S_) ? 2 : 1;
    const int mat0 = (seg == 0) ? 3 : (seg == 2) ? 6 : 0;
    const float* gg = (seg == 0) ? gs : (seg == 2) ? ge : g0;
    const float* bb = (seg == 0) ? bs : (seg == 2) ? be : b0;

    // row stats: 8 threads per row, 64 elems each
    {
        const int rr = tid >> 3, qq = tid & 7;
        const float4* xr = (const float4*)(x + (size_t)(row0 + rr) * DIN) + qq * 16;
        float s = 0.f, s2 = 0.f;
        #pragma unroll
        for (int i = 0; i < 16; ++i) {
            float4 v = xr[i];
            s  += v.x + v.y + v.z + v.w;
            s2 += v.x * v.x + v.y * v.y + v.z * v.z + v.w * v.w;
        }
        s  += __shfl_xor(s, 1);  s  += __shfl_xor(s, 2);  s  += __shfl_xor(s, 4);
        s2 += __shfl_xor(s2, 1); s2 += __shfl_xor(s2, 2); s2 += __shfl_xor(s2, 4);
        if (qq == 0) {
            float mean = s * (1.f / DIN);
            mean_s[rr] = mean;
            rstd_s[rr] = rsqrtf(s2 * (1.f / DIN) - mean * mean + 1e-5f);
        }
    }

    const int w = tid >> 6, lane = tid & 63;
    const int cl = lane & 15, quad = lane >> 4;
    const int r0 = 16 * (w >> 1), c0 = 32 * (w & 1);   // wave: 16 rows x 32 cols

    f32x4 acc[3][2];
    #pragma unroll
    for (int m = 0; m < 3; ++m)
        #pragma unroll
        for (int j = 0; j < 2; ++j) acc[m][j] = 0.f;

    for (int kc = 0; kc < DIN; kc += 64) {
        __syncthreads();
        // stage A (LN'd x, hi/lo split): 32 rows x 8 col-groups = 256 units
        {
            int r = tid >> 3, c8 = tid & 7;
            const float* xp = x + (size_t)(row0 + r) * DIN + kc + c8 * 8;
            float4 a0 = *(const float4*)xp;
            float4 a1 = *(const float4*)(xp + 4);
            float4 gA = *(const float4*)(gg + kc + c8 * 8);
            float4 gB = *(const float4*)(gg + kc + c8 * 8 + 4);
            float4 bA = *(const float4*)(bb + kc + c8 * 8);
            float4 bB = *(const float4*)(bb + kc + c8 * 8 + 4);
            float mean = mean_s[r], rstd = rstd_s[r];
            float n[8];
            n[0] = (a0.x - mean) * rstd * gA.x + bA.x;
            n[1] = (a0.y - mean) * rstd * gA.y + bA.y;
            n[2] = (a0.z - mean) * rstd * gA.z + bA.z;
            n[3] = (a0.w - mean) * rstd * gA.w + bA.w;
            n[4] = (a1.x - mean) * rstd * gB.x + bB.x;
            n[5] = (a1.y - mean) * rstd * gB.y + bB.y;
            n[6] = (a1.z - mean) * rstd * gB.z + bB.z;
            n[7] = (a1.w - mean) * rstd * gB.w + bB.w;
            U4 hi, lo;
            #pragma unroll
            for (int j = 0; j < 8; ++j) {
                hi.h[j] = (f16)n[j];
                lo.h[j] = (f16)(n[j] - (float)hi.h[j]);
            }
            *(uint4*)(As + r * 136 + c8 * 8)      = hi.u;
            *(uint4*)(As + r * 136 + 64 + c8 * 8) = lo.u;
        }
        // stage B for all 3 mats: 3 x 64 cols x 8 groups = 1536 units
        #pragma unroll
        for (int i = 0; i < 6; ++i) {
            int g = tid + 256 * i;
            int mm = g >> 9, rem = g & 511;
            int col = rem >> 3, c8 = rem & 7;
            const f16* src = Wsp + (size_t)(mat0 + mm) * 65536 + (size_t)col * 1024 + kc + c8 * 8;
            f16* dst = Bs + mm * 8704 + col * 136 + c8 * 8;
            *(uint4*)(dst)      = *(const uint4*)(src);
            *(uint4*)(dst + 64) = *(const uint4*)(src + 512);
        }
        __syncthreads();
        #pragma unroll
        for (int h = 0; h < 2; ++h) {
            half8 ah, al;
            {
                const f16* base = As + (r0 + cl) * 136 + h * 32 + quad * 8;
                ah = *(const half8*)(base);
                al = *(const half8*)(base + 64);
            }
            #pragma unroll
            for (int m = 0; m < 3; ++m)
                #pragma unroll
                for (int cs = 0; cs < 2; ++cs) {
                    const f16* base = Bs + m * 8704 + (c0 + 16 * cs + cl) * 136 + h * 32 + quad * 8;
                    half8 bh = *(const half8*)(base);
                    half8 bl = *(const half8*)(base + 64);
                    acc[m][cs] = __builtin_amdgcn_mfma_f32_16x16x32_f16(ah, bh, acc[m][cs], 0, 0, 0);
                    acc[m][cs] = __builtin_amdgcn_mfma_f32_16x16x32_f16(ah, bl, acc[m][cs], 0, 0, 0);
                    acc[m][cs] = __builtin_amdgcn_mfma_f32_16x16x32_f16(al, bh, acc[m][cs], 0, 0, 0);
                }
        }
    }

    const int bI = row0 / L_;
    const int rb = row0 - bI * L_;
    #pragma unroll
    for (int m = 0; m < 3; ++m) {
        f16* sp = (m == 0) ? qsp : ksp;
        #pragma unroll
        for (int cs = 0; cs < 2; ++cs)
            #pragma unroll
            for (int r = 0; r < 4; ++r) {
                int lrow = r0 + quad * 4 + r;
                int col  = c0 + 16 * cs + cl;
                float v  = acc[m][cs][r];
                size_t grow = (size_t)(row0 + lrow);
                if (m < 2) {
                    f16 hv = (f16)v;
                    sp[grow * 128 + col]      = hv;
                    sp[grow * 128 + 64 + col] = (f16)(v - (float)hv);
                } else {
                    vhT[(size_t)(bI * 64 + col) * L_ + rb + lrow] = (f16)v;
                }
            }
    }
}

// ---------------------------------------------------------------------------
// k_dots: mid + edge dots via split-fp16 MFMA (round-2 verified core), PLUS
// li = q.cope folded into the 64 formerly-idle block slots (edge half==0,
// by 1..16). grid (72,18) x 256.
// ---------------------------------------------------------------------------
__global__ __launch_bounds__(256) void k_dots(
    const f16* __restrict__ qsp, const f16* __restrict__ ksp,
    const f16* __restrict__ copesp,
    float* __restrict__ D32, float* __restrict__ G, float* __restrict__ De32,
    float* __restrict__ li32)
{
    const int bx = blockIdx.x, by = blockIdx.y;
    const bool edge = (bx >= 64);
    const int tid = threadIdx.x;
    const int w = tid >> 6, lane = tid & 63;
    const int cl = lane & 15, quad = lane >> 4;

    int b, q0 = 0;
    size_t qrow0;
    if (!edge) {
        if (by >= 17) return;                 // NCOLS = 17 * 128
        b = bx >> 4;
        q0 = (bx * 128) & 2047;
        qrow0 = (size_t)b * L_ + S_ + q0;
    } else {
        int ex = bx - 64;
        b = ex >> 1;
        int half = ex & 1;
        if (half == 0 && by > 0) {
            // ---- li region: 64 blocks (ex in {0,2,4,6}, by 1..16) ----
            if (by > 16) return;
            const int id  = (ex >> 1) * 16 + (by - 1);   // 0..63
            const int gr0 = id * 128;
            const int lb  = gr0 >> 11, lq0 = gr0 & 2047;
            const size_t rowb = (size_t)lb * L_ + S_ + lq0 + 32 * w;

            half8 ah[2][2], al[2][2];
            #pragma unroll
            for (int rs = 0; rs < 2; ++rs)
                #pragma unroll
                for (int h = 0; h < 2; ++h) {
                    const f16* qp = qsp + (rowb + 16 * rs + cl) * 128 + h * 32 + quad * 8;
                    ah[rs][h] = *(const half8*)qp;
                    al[rs][h] = *(const half8*)(qp + 64);
                }
            f32x4 acc[2][8];
            #pragma unroll
            for (int rs = 0; rs < 2; ++rs)
                #pragma unroll
                for (int cf = 0; cf < 8; ++cf) acc[rs][cf] = 0.f;
            #pragma unroll
            for (int h = 0; h < 2; ++h)
                #pragma unroll
                for (int cf = 0; cf < 8; ++cf) {
                    const f16* bbase = copesp + (size_t)(16 * cf + cl) * 128 + h * 32 + quad * 8;
                    half8 bh = *(const half8*)bbase;
                    half8 bl = *(const half8*)(bbase + 64);
                    #pragma unroll
                    for (int rs = 0; rs < 2; ++rs) {
                        acc[rs][cf] = __builtin_amdgcn_mfma_f32_16x16x32_f16(ah[rs][h], bh, acc[rs][cf], 0, 0, 0);
                        acc[rs][cf] = __builtin_amdgcn_mfma_f32_16x16x32_f16(ah[rs][h], bl, acc[rs][cf], 0, 0, 0);
                        acc[rs][cf] = __builtin_amdgcn_mfma_f32_16x16x32_f16(al[rs][h], bh, acc[rs][cf], 0, 0, 0);
                    }
                }
            #pragma unroll
            for (int rs = 0; rs < 2; ++rs)
                #pragma unroll
                for (int cf = 0; cf < 8; ++cf)
                    #pragma unroll
                    for (int r = 0; r < 4; ++r) {
                        int row = gr0 + 32 * w + 16 * rs + quad * 4 + r;
                        li32[(size_t)row * 128 + 16 * cf + cl] = acc[rs][cf][r];
                    }
            return;
        }
        qrow0 = (size_t)b * L_ + (half ? 2176 : 0);
    }
    const int col0 = by * 128;
    const size_t krow0 = (size_t)b * L_ + col0;

    __shared__ f16 Qs[128 * 136];
    __shared__ f16 Ks[128 * 136];

    #pragma unroll
    for (int i = 0; i < 8; ++i) {
        int g = tid + 256 * i;
        int r = g >> 4, c = g & 15;
        *(uint4*)(Qs + r * 136 + c * 8) = *(const uint4*)(qsp + (qrow0 + r) * 128 + c * 8);
        *(uint4*)(Ks + r * 136 + c * 8) = *(const uint4*)(ksp + (krow0 + r) * 128 + c * 8);
    }
    __syncthreads();

    f32x4 acc[2][8];
    #pragma unroll
    for (int i = 0; i < 2; ++i)
        #pragma unroll
        for (int j = 0; j < 8; ++j) acc[i][j] = 0.f;

    #pragma unroll
    for (int h = 0; h < 2; ++h) {
        half8 ah[2], al[2];
        #pragma unroll
        for (int rs = 0; rs < 2; ++rs) {
            const f16* base = Qs + (32 * w + 16 * rs + cl) * 136 + h * 32 + quad * 8;
            ah[rs] = *(const half8*)(base);
            al[rs] = *(const half8*)(base + 64);
        }
        #pragma unroll
        for (int cq = 0; cq < 2; ++cq) {
            half8 bh[4], bl[4];
            #pragma unroll
            for (int cc = 0; cc < 4; ++cc) {
                const f16* base = Ks + (16 * (cq * 4 + cc) + cl) * 136 + h * 32 + quad * 8;
                bh[cc] = *(const half8*)(base);
                bl[cc] = *(const half8*)(base + 64);
            }
            #pragma unroll
            for (int rs = 0; rs < 2; ++rs)
                #pragma unroll
                for (int cc = 0; cc < 4; ++cc) {
                    int c = cq * 4 + cc;
                    acc[rs][c] = __builtin_amdgcn_mfma_f32_16x16x32_f16(ah[rs], bh[cc], acc[rs][c], 0, 0, 0);
                    acc[rs][c] = __builtin_amdgcn_mfma_f32_16x16x32_f16(ah[rs], bl[cc], acc[rs][c], 0, 0, 0);
                    acc[rs][c] = __builtin_amdgcn_mfma_f32_16x16x32_f16(al[rs], bh[cc], acc[rs][c], 0, 0, 0);
                }
        }
    }

    if (!edge) {
        const int gr0 = bx * 128;
        const bool writeD = (by == 0) || ((by - 1) <= (q0 >> 7));
        if (writeD) {
            #pragma unroll
            for (int rs = 0; rs < 2; ++rs)
                #pragma unroll
                for (int c = 0; c < 8; ++c)
                    #pragma unroll
                    for (int r = 0; r < 4; ++r) {
                        int mrow = gr0 + 32 * w + 16 * rs + quad * 4 + r;
                        int n    = col0 + 16 * c + cl;
                        D32[(size_t)mrow * NCOLS + n] = acc[rs][c][r];
                    }
        }
        if (by >= 1) {
            const int chm = 2 * (by - 1);
            #pragma unroll
            for (int rs = 0; rs < 2; ++rs)
                #pragma unroll
                for (int r = 0; r < 4; ++r) {
                    float sA = 0.f, sB = 0.f;
                    #pragma unroll
                    for (int cc = 0; cc < 4; ++cc) {
                        sA += 1.f / (1.f + __expf(-acc[rs][cc][r]));
                        sB += 1.f / (1.f + __expf(-acc[rs][4 + cc][r]));
                    }
                    #pragma unroll
                    for (int off = 1; off < 16; off <<= 1) {
                        sA += __shfl_xor(sA, off);
                        sB += __shfl_xor(sB, off);
                    }
                    if (cl == 0) {
                        int row = gr0 + 32 * w + 16 * rs + quad * 4 + r;
                        G[(size_t)row * 32 + chm]     = sA;
                        G[(size_t)row * 32 + chm + 1] = sB;
                    }
                }
        }
    } else {
        const int er0 = (bx - 64) * 128;
        #pragma unroll
        for (int rs = 0; rs < 2; ++rs)
            #pragma unroll
            for (int c = 0; c < 8; ++c)
                #pragma unroll
                for (int r = 0; r < 4; ++r) {
                    int erow = er0 + 32 * w + 16 * rs + quad * 4 + r;
                    int n    = col0 + 16 * c + cl;
                    De32[(size_t)erow * LE + n] = acc[rs][c][r];
                }
    }
}

// ---------------------------------------------------------------------------
// k_scan: grid 9216 x 256. Reads exact fp32 dots + precomputed li; fp16 P.
// Edge path: loads predicated on causal bound (start rows skip 8/9 groups).
// ---------------------------------------------------------------------------
__global__ __launch_bounds__(256) void k_scan(
    const float* __restrict__ li32, const float* __restrict__ G,
    const float* __restrict__ D32, f16* __restrict__ Dp,
    const float* __restrict__ De32, f16* __restrict__ Dep)
{
    __shared__ float li[128];
    __shared__ float Gs[32];
    __shared__ float Gsf[32];
    __shared__ float wmax[4], wsum[4];
    const int tid = threadIdx.x;
    const int gr  = blockIdx.x;
    const int lane = tid & 63, wid = tid >> 6;

    if (gr < NMID) {
        const int b = gr >> 11;
        const int q = gr & 2047;
        const int qlim = (q & ~63) + 64;

        if (tid < 128) li[tid] = li32[(size_t)gr * 128 + tid];
        if (tid >= 128 && tid < 136)
            ((float4*)Gs)[tid - 128] = ((const float4*)G)[(size_t)gr * 8 + tid - 128];
        __syncthreads();
        if (tid >= 128 && tid < 160) {
            int c = tid - 128;
            float s = 0.f;
            for (int cc = c + 1; cc < 32; ++cc) s += Gs[cc];
            Gsf[c] = s;
        }

        const float* Sr = D32 + (size_t)gr * NCOLS;
        f16* Dr = Dp + (size_t)gr * NCOLS;
        const int j0 = tid * 8;
        const int cg = tid >> 3, sl = tid & 7;
        float dot[8], gte[8];
        float csum = 0.f;
        if (j0 < qlim) {
            float4 t0 = *(const float4*)(Sr + 128 + j0);
            float4 t1 = *(const float4*)(Sr + 128 + j0 + 4);
            dot[0] = t0.x; dot[1] = t0.y; dot[2] = t0.z; dot[3] = t0.w;
            dot[4] = t1.x; dot[5] = t1.y; dot[6] = t1.z; dot[7] = t1.w;
            #pragma unroll
            for (int jj = 0; jj < 8; ++jj) {
                gte[jj] = 1.f / (1.f + __expf(-dot[jj]));
                csum += gte[jj];
            }
        } else {
            #pragma unroll
            for (int jj = 0; jj < 8; ++jj) { dot[jj] = 0.f; gte[jj] = 0.f; }
        }
        float sv = (tid < 128) ? Sr[tid] * SCALE : NEGINF;

        float inc = csum;
        #pragma unroll
        for (int off = 1; off < 8; off <<= 1) {
            float u = __shfl_down(inc, off, 8);
            if (sl + off < 8) inc += u;
        }
        __syncthreads();
        float run = (inc - csum) + Gsf[cg];

        float p8[8];
        #pragma unroll
        for (int jj = 7; jj >= 0; --jj) {
            run += gte[jj];
            float pos = fminf(run, (float)(S_ - 1));
            float pfl = floorf(pos);
            int ic  = (int)ceilf(pos);
            int ifl = (int)pfl;
            float w = pos - pfl;
            float bias = li[ic] * w + li[ifl] * (1.f - w);
            p8[jj] = (j0 + jj <= q) ? dot[jj] * SCALE + bias : NEGINF;
        }

        float mx = sv;
        #pragma unroll
        for (int jj = 0; jj < 8; ++jj) mx = fmaxf(mx, p8[jj]);
        #pragma unroll
        for (int off = 1; off < 64; off <<= 1) mx = fmaxf(mx, __shfl_xor(mx, off));
        if (lane == 0) wmax[wid] = mx;
        __syncthreads();
        mx = fmaxf(fmaxf(wmax[0], wmax[1]), fmaxf(wmax[2], wmax[3]));

        float lsum = 0.f;
        float e8[8];
        #pragma unroll
        for (int jj = 0; jj < 8; ++jj) {
            e8[jj] = __expf(p8[jj] - mx);
            lsum += e8[jj];
        }
        float es = 0.f;
        if (tid < 128) { es = __expf(sv - mx); lsum += es; }
        #pragma unroll
        for (int off = 1; off < 64; off <<= 1) lsum += __shfl_xor(lsum, off);
        if (lane == 0) wsum[wid] = lsum;
        __syncthreads();
        float inv = 1.f / (wsum[0] + wsum[1] + wsum[2] + wsum[3]);

        if (j0 < qlim) {
            U4 o;
            #pragma unroll
            for (int jj = 0; jj < 8; ++jj) o.h[jj] = (f16)(e8[jj] * inv);
            *(uint4*)(Dr + 128 + j0) = o.u;
        }
        if (tid < 128) Dr[tid] = (f16)(es * inv);
    } else {
        const int er = gr - NMID;
        const int r  = er & 255;
        const int Q  = (r < 128) ? r : (2048 + r);
        const float* Er32 = De32 + (size_t)er * LE;
        f16* Er = Dep + (size_t)er * LE;

        float v[9];
        #pragma unroll
        for (int i = 0; i < 9; ++i) {
            int j = tid + 256 * i;
            v[i] = (j <= Q) ? Er32[j] * SCALE : NEGINF;   // predicated load
        }
        float mx = v[0];
        #pragma unroll
        for (int i = 1; i < 9; ++i) mx = fmaxf(mx, v[i]);
        #pragma unroll
        for (int off = 1; off < 64; off <<= 1) mx = fmaxf(mx, __shfl_xor(mx, off));
        if (lane == 0) wmax[wid] = mx;
        __syncthreads();
        mx = fmaxf(fmaxf(wmax[0], wmax[1]), fmaxf(wmax[2], wmax[3]));

        float lsum = 0.f;
        #pragma unroll
        for (int i = 0; i < 9; ++i) {
            v[i] = __expf(v[i] - mx);
            lsum += v[i];
        }
        #pragma unroll
        for (int off = 1; off < 64; off <<= 1) lsum += __shfl_xor(lsum, off);
        if (lane == 0) wsum[wid] = lsum;
        __syncthreads();
        float inv = 1.f / (wsum[0] + wsum[1] + wsum[2] + wsum[3]);

        #pragma unroll
        for (int i = 0; i < 9; ++i)
            Er[tid + 256 * i] = (f16)(v[i] * inv);
    }
}

// ---------------------------------------------------------------------------
// k_pv (round-2 verified): mid + edge PV via fp16 MFMA, 4-way K-split,
// partial stores. grid (144, 4) x 256. bx<128: mid. bx>=128: edge.
// ---------------------------------------------------------------------------
__global__ __launch_bounds__(256) void k_pv(
    const f16* __restrict__ Pmid, const f16* __restrict__ Pedge,
    const f16* __restrict__ vhT,
    float* __restrict__ Opart, float* __restrict__ Oe)
{
    __shared__ f16 Ps[64 * 72];
    __shared__ f16 Vt[64 * 72];
    const int tid = threadIdx.x;
    const int bx  = blockIdx.x;
    const int ks  = blockIdx.y;
    const bool edge = (bx >= 128);

    const f16* Pb;
    size_t pitch;
    int row0, b, cap, cmax;
    float* outp;
    if (!edge) {
        row0 = bx * 64;
        b = row0 >> 11;
        int q0 = row0 & 2047;
        Pb = Pmid; pitch = NCOLS; cap = 34;
        cmax = (191 + q0) >> 6;
        outp = Opart + (size_t)ks * NMID * DK;
    } else {
        row0 = (bx - 128) * 64;
        b = row0 >> 8;
        int r0 = row0 & 255;
        Pb = Pedge; pitch = LE; cap = 36;
        int Qmax = (r0 < 128) ? (r0 + 63) : (2048 + r0 + 63);
        cmax = Qmax >> 6;
        outp = Oe + (size_t)ks * NEDGE * DK;
    }
    const int c_beg = ks * 9;
    int c_end = c_beg + 9;
    if (c_end > cap) c_end = cap;
    if (c_end > cmax + 1) c_end = cmax + 1;

    const int w = tid >> 6, lane = tid & 63;
    const int cl = lane & 15, quad = lane >> 4;
    f32x4 acc[4];
    #pragma unroll
    for (int c = 0; c < 4; ++c) acc[c] = 0.f;

    for (int ch = c_beg; ch < c_end; ++ch) {
        __syncthreads();
        #pragma unroll
        for (int i = 0; i < 2; ++i) {
            int g = tid + 256 * i;
            int r = g >> 3, c = g & 7;
            *(uint4*)(Ps + r * 72 + c * 8) =
                *(const uint4*)(Pb + (size_t)(row0 + r) * pitch + ch * 64 + c * 8);
            *(uint4*)(Vt + r * 72 + c * 8) =
                *(const uint4*)(vhT + (size_t)(b * 64 + r) * L_ + ch * 64 + c * 8);
        }
        __syncthreads();
        #pragma unroll
        for (int h = 0; h < 2; ++h) {
            half8 a = *(const half8*)(Ps + (16 * w + cl) * 72 + h * 32 + quad * 8);
            #pragma unroll
            for (int c = 0; c < 4; ++c) {
                half8 bv = *(const half8*)(Vt + (16 * c + cl) * 72 + h * 32 + quad * 8);
                acc[c] = __builtin_amdgcn_mfma_f32_16x16x32_f16(a, bv, acc[c], 0, 0, 0);
            }
        }
    }
    #pragma unroll
    for (int c = 0; c < 4; ++c)
        #pragma unroll
        for (int r = 0; r < 4; ++r) {
            int mrow = row0 + 16 * w + quad * 4 + r;
            int n    = 16 * c + cl;
            outp[(size_t)mrow * DK + n] = acc[c][r];
        }
}

// ---------------------------------------------------------------------------
// k_merge (round-2 verified): sum 4 partials, mid + edge. grid 2304 x 256.
// ---------------------------------------------------------------------------
__global__ __launch_bounds__(256) void k_merge(
    const float* __restrict__ Opart, const float* __restrict__ Oe,
    float* __restrict__ out)
{
    const int e = blockIdx.x * 256 + threadIdx.x;
    if (e < NMID * DK) {
        const int gr = e >> 6, c = e & 63;
        const int b  = gr >> 11, q = gr & 2047;
        const int NP = NMID * DK;
        float s = Opart[e] + Opart[e + NP] + Opart[e + 2 * NP] + Opart[e + 3 * NP];
        out[((size_t)b * L_ + S_ + q) * DK + c] = s;
    } else {
        const int e2 = e - NMID * DK;
        const int er = e2 >> 6, c = e2 & 63;
        const int b  = er >> 8, r = er & 255;
        const int gQ = (r < 128) ? r : (2048 + r);
        const int NP = NEDGE * DK;
        float s = Oe[e2] + Oe[e2 + NP] + Oe[e2 + 2 * NP] + Oe[e2 + 3 * NP];
        out[((size_t)b * L_ + gQ) * DK + c] = s;
    }
}

// ---------------------------------------------------------------------------
extern "C" void kernel_launch(void* const* d_in, const int* in_sizes, int n_in,
                              void* d_out, int out_size, void* d_ws, size_t ws_size,
                              hipStream_t stream)
{
    const float* x    = (const float*)d_in[0];
    const float* Wq   = (const float*)d_in[1];
    const float* Wk   = (const float*)d_in[2];
    const float* Wv   = (const float*)d_in[3];
    const float* Wqs  = (const float*)d_in[4];
    const float* Wks  = (const float*)d_in[5];
    const float* Wvs  = (const float*)d_in[6];
    const float* Wqe  = (const float*)d_in[7];
    const float* Wke  = (const float*)d_in[8];
    const float* Wve  = (const float*)d_in[9];
    const float* g0   = (const float*)d_in[10];
    const float* b0   = (const float*)d_in[11];
    const float* gs   = (const float*)d_in[12];
    const float* bs   = (const float*)d_in[13];
    const float* ge   = (const float*)d_in[14];
    const float* be   = (const float*)d_in[15];
    const float* cope = (const float*)d_in[16];

    const size_t NR = (size_t)B_ * L_;                 // 9216 rows
    f16*   qsp    = (f16*)d_ws;                        // NR*128 h (hi|lo)
    f16*   ksp    = qsp + NR * 128;                    // NR*128 h
    f16*   vhT    = ksp + NR * 128;                    // NR*64 h
    f16*   Wsp    = vhT + NR * 64;                     // 9*65536 h
    f16*   copesp = Wsp + (size_t)9 * 65536;           // 128*128 h
    float* G      = (float*)(copesp + 16384);          // NMID*32 f32
    float* li32   = G + (size_t)NMID * 32;             // NMID*128 f32
    float* Opart  = li32 + (size_t)NMID * 128;         // 4*NMID*64 f32
    float* Oe     = Opart + (size_t)4 * NMID * DK;     // 4*NEDGE*64 f32
    float* Dm32   = Oe + (size_t)4 * NEDGE * DK;       // NMID*NCOLS f32
    float* De32   = Dm32 + (size_t)NMID * NCOLS;       // NEDGE*LE f32
    f16*   Dp     = (f16*)(De32 + (size_t)NEDGE * LE); // NMID*NCOLS h (P)
    f16*   Dep    = Dp + (size_t)NMID * NCOLS;         // NEDGE*LE h (P)
    float* out    = (float*)d_out;

    k_wsplit<<<dim3(8, 10), 256, 0, stream>>>(Wq, Wk, Wv, Wqs, Wks, Wvs,
                                              Wqe, Wke, Wve, cope, Wsp, copesp);
    k_proj<<<288, 256, 0, stream>>>(x, Wsp, g0, b0, gs, bs, ge, be,
                                    qsp, ksp, vhT);
    k_dots<<<dim3(72, 18), 256, 0, stream>>>(qsp, ksp, copesp, Dm32, G, De32, li32);
    k_scan<<<NMID + NEDGE, 256, 0, stream>>>(li32, G, Dm32, Dp, De32, Dep);
    k_pv  <<<dim3(144, 4), 256, 0, stream>>>(Dp, Dep, vhT, Opart, Oe);
    k_merge<<<(NMID + NEDGE) * DK / 256, 256, 0, stream>>>(Opart, Oe, out);
}